// Round 4
// baseline (255.578 us; speedup 1.0000x reference)
//
#include <hip/hip_runtime.h>
#include <hip/hip_bf16.h>

#define E_MSGS 131072
#define N_NODES 8192
#define D_DIM 256
#define XA_STRIDE 264  // 256 + 8 bf16 pad for A-frag ds_read_b128

typedef __bf16 bf16x8 __attribute__((ext_vector_type(8)));
typedef float f32x4 __attribute__((ext_vector_type(4)));

// raw workgroup barrier: drains LDS (lgkm) only — vmem prefetch stays in flight
#define BAR() asm volatile("s_waitcnt lgkmcnt(0)\n\ts_barrier" ::: "memory")

// ============ phase 1: padded-bucket scatter + (V,c2,perm) + in-place sort =====

__global__ void k_scatter(const int* __restrict__ index, int* __restrict__ cursors,
                          int* __restrict__ pad) {
    int e = blockIdx.x * blockDim.x + threadIdx.x;
    int n = index[e];
    int p = atomicAdd(&cursors[n], 1);
    if (p < 64) pad[(n << 6) + p] = e;
}

// blocks 0..255: V = W^2 (fp32) + c2 = W b + b.  block 256: count-desc perm.
__global__ void k_prep2(const float* __restrict__ W, const float* __restrict__ b,
                        const int* __restrict__ counts, float* __restrict__ V,
                        float* __restrict__ c2, int* __restrict__ perm) {
    int tid = threadIdx.x;
    if (blockIdx.x < 256) {
        int i = blockIdx.x, j = tid;
        // c2[i] = sum_k W[i][k] b[k] + b[i]  (block tree-reduce)
        __shared__ float red[256];
        red[j] = W[i * 256 + j] * b[j];
        __syncthreads();
        for (int s = 128; s > 0; s >>= 1) {
            if (j < s) red[j] += red[j + s];
            __syncthreads();
        }
        if (j == 0) c2[i] = red[0] + b[i];
        // V[i][j] = sum_k W[i][k] W[k][j]  (wi uniform/scalar, wkj coalesced)
        float acc = 0.f;
        for (int k = 0; k < 256; k += 4) {
            float4 wi = *(const float4*)(W + i * 256 + k);
            acc += wi.x * W[(k + 0) * 256 + j];
            acc += wi.y * W[(k + 1) * 256 + j];
            acc += wi.z * W[(k + 2) * 256 + j];
            acc += wi.w * W[(k + 3) * 256 + j];
        }
        V[i * 256 + j] = acc;
    } else {
        // count-desc node permutation (groups similar-count nodes per block)
        __shared__ int hist[65];
        __shared__ int hcur[65];
        if (tid < 65) hist[tid] = 0;
        __syncthreads();
        int myc[32];
#pragma unroll
        for (int i = 0; i < 32; i++) {
            int c = min(counts[tid * 32 + i], 64);
            myc[i] = c;
            atomicAdd(&hist[c], 1);
        }
        __syncthreads();
        if (tid == 0) {
            int run = 0;
            for (int c = 64; c >= 0; c--) { hcur[c] = run; run += hist[c]; }
        }
        __syncthreads();
#pragma unroll
        for (int i = 0; i < 32; i++) {
            int pos = atomicAdd(&hcur[myc[i]], 1);
            perm[pos] = tid * 32 + i;
        }
    }
}

// one wave per node: rank-sort pad row by (t asc, id asc) in place (cnt<=64)
__global__ void k_sortseg(const float* __restrict__ t, const int* __restrict__ counts,
                          int* __restrict__ pad) {
    int wid = (blockIdx.x * 256 + threadIdx.x) >> 6;
    int ln = threadIdx.x & 63;
    int cnt = min(counts[wid], 64);
    int base = wid << 6;
    int e = 0; float tv = 0.f;
    if (ln < cnt) { e = pad[base + ln]; tv = t[e]; }
    int rank = 0;
    for (int j = 0; j < cnt; j++) {
        float tj = __shfl(tv, j);
        int ej = __shfl(e, j);
        rank += (tj < tv) || (tj == tv && ej < e);
    }
    if (ln < cnt) pad[base + rank] = e;
}

// ================= phase 2: DOUBLE-STEP recurrence =================
// h_{s+2} = V(m_s + h_s) + W m_{s+1} + c2,  V = W^2, c2 = Wb + b.
// Halves the serial chain: one LDS round-trip + one barrier per 2 messages,
// and the W*y MFMAs (h-independent) fill the pipe behind the V*x chain.
// Odd-count nodes take one masked single W-step in the prologue, so the loop
// is uniform doubles with per-node d<dlim masks. 16 nodes/block, 8 waves x
// 32 dims; wfV+wfW = 128 VGPR -> ~220 total -> 2 waves/SIMD, 1 block/CU.

__launch_bounds__(512, 2)
__global__ void k_gru2(const float* __restrict__ msg, const float* __restrict__ W,
                       const float* __restrict__ V, const float* __restrict__ b,
                       const float* __restrict__ c2, const int* __restrict__ counts,
                       const int* __restrict__ spad, const int* __restrict__ perm,
                       float* __restrict__ out) {
    __shared__ __bf16 xB[2][16 * XA_STRIDE];
    __shared__ __bf16 yB[2][16 * XA_STRIDE];

    int tid  = threadIdx.x;
    int wave = tid >> 6, lane = tid & 63, q = lane >> 4, l = lane & 15;
    int node0 = blockIdx.x * 16;
    int col[2] = {32 * wave + l, 32 * wave + 16 + l};

    // ---- B-operand fragments for W and V (B[k][n]=M[n][k]) ----
    bf16x8 wfW[8][2], wfV[8][2];
#pragma unroll
    for (int t = 0; t < 2; t++) {
        const float* wr = W + (long)col[t] * D_DIM;
        const float* vr = V + (long)col[t] * D_DIM;
#pragma unroll
        for (int c = 0; c < 8; c++) {
            int k0 = 32 * c + 8 * q;
            float4 w0 = *(const float4*)(wr + k0);
            float4 w1 = *(const float4*)(wr + k0 + 4);
            bf16x8 f;
            f[0] = (__bf16)w0.x; f[1] = (__bf16)w0.y; f[2] = (__bf16)w0.z; f[3] = (__bf16)w0.w;
            f[4] = (__bf16)w1.x; f[5] = (__bf16)w1.y; f[6] = (__bf16)w1.z; f[7] = (__bf16)w1.w;
            wfW[c][t] = f;
            float4 v0 = *(const float4*)(vr + k0);
            float4 v1 = *(const float4*)(vr + k0 + 4);
            bf16x8 g;
            g[0] = (__bf16)v0.x; g[1] = (__bf16)v0.y; g[2] = (__bf16)v0.z; g[3] = (__bf16)v0.w;
            g[4] = (__bf16)v1.x; g[5] = (__bf16)v1.y; g[6] = (__bf16)v1.z; g[7] = (__bf16)v1.w;
            wfV[c][t] = g;
        }
    }
    float bias[2]  = {b[col[0]], b[col[1]]};
    float bias2[2] = {c2[col[0]], c2[col[1]]};

    // quad q owns C/D rows 4q+r -> nodes perm[node0+4q+r]
    int base4[4], o4[4], dlim[4];
#pragma unroll
    for (int r = 0; r < 4; r++) {
        int n = perm[node0 + 4 * q + r];
        base4[r] = n << 6;
        int c = min(counts[n], 64);
        o4[r] = c & 1;
        dlim[r] = (c - o4[r]) >> 1;
    }
    int D = min(counts[perm[node0]], 64) >> 1;  // count-desc: block max doubles

    // ---- prologue ----
    // load m_0 (prologue step, odd nodes) and m_{o..o+3}
    float m_pro[4][2], mx0[4][2], my0[4][2], mA[4][2], mA2[4][2];
    __bf16 mB[4][2], mB2[4][2];
    int sidN[4][2];
#pragma unroll
    for (int r = 0; r < 4; r++) {
        int o = o4[r];
        int s_pro = spad[base4[r]];
        int sx = spad[base4[r] + o];
        int sy = spad[base4[r] + o + 1];
        int sA = spad[base4[r] + o + 2];
        int sB = spad[base4[r] + o + 3];
        const float* mp = msg + (long)s_pro * D_DIM;
        const float* mx = msg + (long)sx * D_DIM;
        const float* my = msg + (long)sy * D_DIM;
        const float* ma = msg + (long)sA * D_DIM;
        const float* mb = msg + (long)sB * D_DIM;
#pragma unroll
        for (int t = 0; t < 2; t++) {
            m_pro[r][t] = mp[col[t]];
            mx0[r][t]   = mx[col[t]];
            my0[r][t]   = my[col[t]];
            mA[r][t]    = ma[col[t]];
            mB[r][t]    = (__bf16)mb[col[t]];
        }
        sidN[r][0] = spad[base4[r] + min(o + 4, 63)];
        sidN[r][1] = spad[base4[r] + min(o + 5, 63)];
    }
    // prologue A-tile = m_0
#pragma unroll
    for (int t = 0; t < 2; t++)
#pragma unroll
        for (int r = 0; r < 4; r++)
            xB[0][(4 * q + r) * XA_STRIDE + col[t]] = (__bf16)m_pro[r][t];
    BAR();
    // prologue single W-step (applies only to odd-count nodes)
    f32x4 accP[2];
#pragma unroll
    for (int t = 0; t < 2; t++) accP[t] = (f32x4){0.f, 0.f, 0.f, 0.f};
#pragma unroll
    for (int c = 0; c < 8; c++) {
        bf16x8 a = *(const bf16x8*)(&xB[0][0] + l * XA_STRIDE + 32 * c + 8 * q);
#pragma unroll
        for (int t = 0; t < 2; t++)
            accP[t] = __builtin_amdgcn_mfma_f32_16x16x32_bf16(a, wfW[c][t], accP[t], 0, 0, 0);
    }
    float h[2][4];
#pragma unroll
    for (int t = 0; t < 2; t++)
#pragma unroll
        for (int r = 0; r < 4; r++)
            h[t][r] = o4[r] ? (accP[t][r] + bias[t]) : 0.f;
    // x_0 = m_o + h, y_0 = m_{o+1} -> buffer 1 (step d reads (d+1)&1)
#pragma unroll
    for (int t = 0; t < 2; t++)
#pragma unroll
        for (int r = 0; r < 4; r++) {
            xB[1][(4 * q + r) * XA_STRIDE + col[t]] = (__bf16)(h[t][r] + mx0[r][t]);
            yB[1][(4 * q + r) * XA_STRIDE + col[t]] = (__bf16)my0[r][t];
        }
    BAR();

    // one double-step: consume {cA,cB} (= m_{o+2d+2}, m_{o+2d+3}), load next set
    auto dstep = [&](int d, float (&cA)[4][2], __bf16 (&cB)[4][2],
                     float (&nA)[4][2], __bf16 (&nB)[4][2]) {
        // prefetch msgs for the NEXT double (positions o+2d+4, o+2d+5)
#pragma unroll
        for (int r = 0; r < 4; r++) {
            const float* ma = msg + (long)sidN[r][0] * D_DIM;
            const float* mb = msg + (long)sidN[r][1] * D_DIM;
#pragma unroll
            for (int t = 0; t < 2; t++) {
                nA[r][t] = ma[col[t]];
                nB[r][t] = (__bf16)mb[col[t]];
            }
        }
#pragma unroll
        for (int r = 0; r < 4; r++) {
            sidN[r][0] = spad[base4[r] + min(o4[r] + 2 * d + 6, 63)];
            sidN[r][1] = spad[base4[r] + min(o4[r] + 2 * d + 7, 63)];
        }
        int rb = (d + 1) & 1, wb = d & 1;
        // acc = V*x_d + W*y_d (two 8-deep chains, summed at the end)
        f32x4 accX[2], accY[2];
#pragma unroll
        for (int t = 0; t < 2; t++) {
            accX[t] = (f32x4){0.f, 0.f, 0.f, 0.f};
            accY[t] = (f32x4){0.f, 0.f, 0.f, 0.f};
        }
#pragma unroll
        for (int c = 0; c < 8; c++) {
            bf16x8 ax = *(const bf16x8*)(&xB[rb][0] + l * XA_STRIDE + 32 * c + 8 * q);
#pragma unroll
            for (int t = 0; t < 2; t++)
                accX[t] = __builtin_amdgcn_mfma_f32_16x16x32_bf16(ax, wfV[c][t], accX[t], 0, 0, 0);
        }
#pragma unroll
        for (int c = 0; c < 8; c++) {
            bf16x8 ay = *(const bf16x8*)(&yB[rb][0] + l * XA_STRIDE + 32 * c + 8 * q);
#pragma unroll
            for (int t = 0; t < 2; t++)
                accY[t] = __builtin_amdgcn_mfma_f32_16x16x32_bf16(ay, wfW[c][t], accY[t], 0, 0, 0);
        }
        // h update (masked) + write x_{d+1}, y_{d+1}
#pragma unroll
        for (int t = 0; t < 2; t++) {
#pragma unroll
            for (int r = 0; r < 4; r++) {
                float hn = accX[t][r] + accY[t][r] + bias2[t];
                bool valid = d < dlim[r];
                h[t][r] = valid ? hn : h[t][r];
                xB[wb][(4 * q + r) * XA_STRIDE + col[t]] = (__bf16)(h[t][r] + cA[r][t]);
                yB[wb][(4 * q + r) * XA_STRIDE + col[t]] = cB[r][t];
            }
        }
        BAR();
    };

    int d = 0;
    while (d < D) {
        dstep(d, mA, mB, mA2, mB2);
        d++;
        if (d >= D) break;
        dstep(d, mA2, mB2, mA, mB);
        d++;
    }

    // ---- write fp32 h (0 for empty nodes) ----
#pragma unroll
    for (int r = 0; r < 4; r++) {
        int n = perm[node0 + 4 * q + r];
#pragma unroll
        for (int t = 0; t < 2; t++)
            out[(long)n * D_DIM + col[t]] = h[t][r];
    }
}

// ================= launch =================

extern "C" void kernel_launch(void* const* d_in, const int* in_sizes, int n_in,
                              void* d_out, int out_size, void* d_ws, size_t ws_size,
                              hipStream_t stream) {
    const float* msg   = (const float*)d_in[0];
    const int*   index = (const int*)d_in[1];
    const float* t     = (const float*)d_in[2];
    const float* W     = (const float*)d_in[4];
    const float* b     = (const float*)d_in[5];
    float* out = (float*)d_out;

    int* ws = (int*)d_ws;
    int* cursors = ws;                      // [8192] -> ends as counts
    int* pad     = ws + 8192;               // [8192*64]
    int* perm    = ws + 8192 + 8192 * 64;   // [8192]
    float* V     = (float*)(perm + 8192);   // [256*256]
    float* c2    = V + 65536;               // [256]

    // zero cursors + pad in one memset (pad zeros make rows >= cnt safe)
    hipMemsetAsync(cursors, 0, (8192 + 8192 * 64) * sizeof(int), stream);

    k_scatter<<<E_MSGS / 256, 256, 0, stream>>>(index, cursors, pad);
    k_prep2<<<257, 256, 0, stream>>>(W, b, cursors, V, c2, perm);
    k_sortseg<<<N_NODES * 64 / 256, 256, 0, stream>>>(t, cursors, pad);
    k_gru2<<<N_NODES / 16, 512, 0, stream>>>(msg, W, V, b, c2, cursors, pad, perm, out);
}

// Round 5
// 249.222 us; speedup vs baseline: 1.0255x; 1.0255x over previous
//
#include <hip/hip_runtime.h>
#include <hip/hip_bf16.h>

#define E_MSGS 131072
#define N_NODES 8192
#define D_DIM 256
#define XA_STRIDE 264  // 256 + 8 bf16 pad for ds_read_b128 A-frags

typedef __bf16 bf16x8 __attribute__((ext_vector_type(8)));
typedef float f32x4 __attribute__((ext_vector_type(4)));

// raw workgroup barrier: drains LDS (lgkm) only — vmem prefetch stays in flight
#define BAR() asm volatile("s_waitcnt lgkmcnt(0)\n\ts_barrier" ::: "memory")

// ============ phase 1: padded-bucket scatter + fused sort/perm ============

__global__ void k_scatter(const int* __restrict__ index, int* __restrict__ cursors,
                          int* __restrict__ pad) {
    int e = blockIdx.x * blockDim.x + threadIdx.x;
    int n = index[e];
    int p = atomicAdd(&cursors[n], 1);
    if (p < 64) pad[(n << 6) + p] = e;
}

// blocks 0..2047: one wave per node, rank-sort pad row by (t asc, id asc) in place.
// block 2048: count-desc node permutation.
__global__ void k_sortperm(const float* __restrict__ t, const int* __restrict__ counts,
                           int* __restrict__ pad, int* __restrict__ perm) {
    int tid = threadIdx.x;
    if (blockIdx.x < 2048) {
        int wid = (blockIdx.x * 256 + tid) >> 6;
        int ln = tid & 63;
        int cnt = min(counts[wid], 64);
        int base = wid << 6;
        int e = 0; float tv = 0.f;
        if (ln < cnt) { e = pad[base + ln]; tv = t[e]; }
        int rank = 0;
        for (int j = 0; j < cnt; j++) {
            float tj = __shfl(tv, j);
            int ej = __shfl(e, j);
            rank += (tj < tv) || (tj == tv && ej < e);  // stable: tie -> orig id
        }
        if (ln < cnt) pad[base + rank] = e;
    } else {
        __shared__ int hist[65];
        __shared__ int hcur[65];
        if (tid < 65) hist[tid] = 0;
        __syncthreads();
        int myc[32];
#pragma unroll
        for (int i = 0; i < 32; i++) {
            int c = min(counts[tid * 32 + i], 64);
            myc[i] = c;
            atomicAdd(&hist[c], 1);
        }
        __syncthreads();
        if (tid == 0) {
            int run = 0;
            for (int c = 64; c >= 0; c--) { hcur[c] = run; run += hist[c]; }
        }
        __syncthreads();
#pragma unroll
        for (int i = 0; i < 32; i++) {
            int pos = atomicAdd(&hcur[myc[i]], 1);
            perm[pos] = tid * 32 + i;
        }
    }
}

// ================= phase 2: serial recurrence, coalesced LDS msg staging =======
// r3 structure (8 waves x 32 dims, W in regs, per-step MFMA) with ONE change:
// the msg path. Wave w owns x-cols [32w,32w+32). Its lanes load m rows as two
// coalesced float4s (lane -> row=ln>>2, 32B chunk=ln&3) and write bf16 directly
// into the x-buffer TWO steps ahead (3-buffer rotation -> race-free, no new
// barriers). The epilogue h-add becomes a same-wave LDS RMW (u16 reads, 120cy)
// replacing the old per-lane scattered global dword gather (~900cy, divergent
// addresses) that r0-r4 never varied while per-message cost stayed ~3200cy.

__launch_bounds__(512, 4)
__global__ void k_gru(const float* __restrict__ msg, const float* __restrict__ W,
                      const float* __restrict__ b, const int* __restrict__ counts,
                      const int* __restrict__ spad, const int* __restrict__ perm,
                      float* __restrict__ out) {
    __shared__ __bf16 xA[3][16 * XA_STRIDE];

    int tid  = threadIdx.x;
    int wave = tid >> 6;   // 0..7
    int lane = tid & 63;
    int q    = lane >> 4;
    int l    = lane & 15;
    int node0 = blockIdx.x * 16;

    // ---- W fragments (B operand: B[k][n]=W[n][k]; lane n=32w+16t+l, k=32c+8q+j) ----
    bf16x8 wf[8][2];
#pragma unroll
    for (int t4 = 0; t4 < 2; t4++) {
        const float* wr = W + (32 * wave + 16 * t4 + l) * D_DIM;
#pragma unroll
        for (int c = 0; c < 8; c++) {
            int k0 = 32 * c + 8 * q;
            float4 w0 = *(const float4*)(wr + k0);
            float4 w1 = *(const float4*)(wr + k0 + 4);
            bf16x8 f;
            f[0] = (__bf16)w0.x; f[1] = (__bf16)w0.y; f[2] = (__bf16)w0.z; f[3] = (__bf16)w0.w;
            f[4] = (__bf16)w1.x; f[5] = (__bf16)w1.y; f[6] = (__bf16)w1.z; f[7] = (__bf16)w1.w;
            wf[c][t4] = f;
        }
    }
    float bias[2];
#pragma unroll
    for (int t4 = 0; t4 < 2; t4++) bias[t4] = b[32 * wave + 16 * t4 + l];

    // C-lane node info: quad q owns rows 4q+r -> nodes perm[node0+4q+r]
    int cnt4[4];
#pragma unroll
    for (int r = 0; r < 4; r++) cnt4[r] = min(counts[perm[node0 + 4 * q + r]], 64);
    int S = min(counts[perm[node0]], 64);  // count-desc: first node = block max

    // loader-lane info: lane handles row jrow (0..15), 32B chunk k4 of its cols
    int jrow = lane >> 2;
    int k4 = lane & 3;
    long baseL = (long)perm[node0 + jrow] << 6;  // broadcast x4 lanes
    int colL = 32 * wave + 8 * k4;

    float h[2][4];
#pragma unroll
    for (int t4 = 0; t4 < 2; t4++)
#pragma unroll
        for (int r = 0; r < 4; r++) h[t4][r] = 0.f;

    // ---- prologue: m_0 -> xA[0], m_1 -> xA[1], mf = m_2, sidR = sid_3 ----
    int sid0 = spad[baseL + 0];
    int sid1 = spad[baseL + 1];
    int sid2 = spad[baseL + 2];
    int sidR = spad[baseL + 3];
    float4 mf0, mf1;
    {
        const float* m0 = msg + (long)sid0 * D_DIM + colL;
        const float* m1 = msg + (long)sid1 * D_DIM + colL;
        const float* m2 = msg + (long)sid2 * D_DIM + colL;
        float4 a0 = *(const float4*)m0, a1 = *(const float4*)(m0 + 4);
        float4 b0 = *(const float4*)m1, b1 = *(const float4*)(m1 + 4);
        mf0 = *(const float4*)m2; mf1 = *(const float4*)(m2 + 4);
        bf16x8 fa, fb;
        fa[0] = (__bf16)a0.x; fa[1] = (__bf16)a0.y; fa[2] = (__bf16)a0.z; fa[3] = (__bf16)a0.w;
        fa[4] = (__bf16)a1.x; fa[5] = (__bf16)a1.y; fa[6] = (__bf16)a1.z; fa[7] = (__bf16)a1.w;
        fb[0] = (__bf16)b0.x; fb[1] = (__bf16)b0.y; fb[2] = (__bf16)b0.z; fb[3] = (__bf16)b0.w;
        fb[4] = (__bf16)b1.x; fb[5] = (__bf16)b1.y; fb[6] = (__bf16)b1.z; fb[7] = (__bf16)b1.w;
        *(bf16x8*)(&xA[0][jrow * XA_STRIDE + colL]) = fa;
        *(bf16x8*)(&xA[1][jrow * XA_STRIDE + colL]) = fb;
    }
    BAR();

    // step s: read xA[rb]=x_s; epilogue RMW h into xA[hb] (holds m_{s+1});
    // loader writes mf (m_{s+2}) into xA[mb]; then loads mf = m_{s+3}.
    auto step = [&](int s, int rb, int hb, int mb) {
        // (i) publish m_{s+2} (regs -> LDS; buffer mb was last read at step s-1)
        {
            bf16x8 f;
            f[0] = (__bf16)mf0.x; f[1] = (__bf16)mf0.y; f[2] = (__bf16)mf0.z; f[3] = (__bf16)mf0.w;
            f[4] = (__bf16)mf1.x; f[5] = (__bf16)mf1.y; f[6] = (__bf16)mf1.z; f[7] = (__bf16)mf1.w;
            *(bf16x8*)(&xA[mb][jrow * XA_STRIDE + colL]) = f;
        }
        // (ii) prefetch m_{s+3} (coalesced float4 pair), advance sid chain
        {
            const float* mrow = msg + (long)sidR * D_DIM + colL;
            mf0 = *(const float4*)mrow;
            mf1 = *(const float4*)(mrow + 4);
            sidR = spad[baseL + min(s + 4, 63)];
        }
        // (iii) MFMA: acc = x_s @ W^T
        const __bf16* buf = xA[rb];
        f32x4 acc[2];
#pragma unroll
        for (int t4 = 0; t4 < 2; t4++) acc[t4] = (f32x4){0.f, 0.f, 0.f, 0.f};
#pragma unroll
        for (int c = 0; c < 8; c++) {
            bf16x8 a = *(const bf16x8*)(buf + l * XA_STRIDE + 32 * c + 8 * q);
#pragma unroll
            for (int t4 = 0; t4 < 2; t4++)
                acc[t4] = __builtin_amdgcn_mfma_f32_16x16x32_bf16(a, wf[c][t4], acc[t4], 0, 0, 0);
        }
        // (iv) epilogue: h update (masked) + same-wave LDS RMW x_{s+1} = m + h
#pragma unroll
        for (int t4 = 0; t4 < 2; t4++) {
#pragma unroll
            for (int r = 0; r < 4; r++) {
                float hn = acc[t4][r] + bias[t4];
                bool valid = s < cnt4[r];
                h[t4][r] = valid ? hn : h[t4][r];
                int off = (4 * q + r) * XA_STRIDE + 32 * wave + 16 * t4 + l;
                float mval = (float)xA[hb][off];
                xA[hb][off] = (__bf16)(h[t4][r] + mval);
            }
        }
        BAR();
    };

    int s = 0;
    while (true) {
        if (s >= S) break; step(s, 0, 1, 2); s++;
        if (s >= S) break; step(s, 1, 2, 0); s++;
        if (s >= S) break; step(s, 2, 0, 1); s++;
    }

    // ---- write fp32 h (0 for empty nodes) ----
#pragma unroll
    for (int r = 0; r < 4; r++) {
        int n = perm[node0 + 4 * q + r];
#pragma unroll
        for (int t4 = 0; t4 < 2; t4++)
            out[(long)n * D_DIM + 32 * wave + 16 * t4 + l] = h[t4][r];
    }
}

// ================= launch =================

extern "C" void kernel_launch(void* const* d_in, const int* in_sizes, int n_in,
                              void* d_out, int out_size, void* d_ws, size_t ws_size,
                              hipStream_t stream) {
    const float* msg   = (const float*)d_in[0];
    const int*   index = (const int*)d_in[1];
    const float* t     = (const float*)d_in[2];
    const float* W     = (const float*)d_in[4];
    const float* b     = (const float*)d_in[5];
    float* out = (float*)d_out;

    int* ws = (int*)d_ws;
    int* cursors = ws;                      // [8192] -> ends as counts
    int* pad     = ws + 8192;               // [8192*64]
    int* perm    = ws + 8192 + 8192 * 64;   // [8192]

    // zero cursors + pad in one memset (pad zeros make rows >= cnt safe)
    hipMemsetAsync(cursors, 0, (8192 + 8192 * 64) * sizeof(int), stream);

    k_scatter<<<E_MSGS / 256, 256, 0, stream>>>(index, cursors, pad);
    k_sortperm<<<2049, 256, 0, stream>>>(t, cursors, pad, perm);
    k_gru<<<N_NODES / 16, 512, 0, stream>>>(msg, W, b, cursors, pad, perm, out);
}